// Round 7
// baseline (73.352 us; speedup 1.0000x reference)
//
#include <hip/hip_runtime.h>
#include <hip/hip_bf16.h>
#include <math.h>

#define N_TOK 4096
#define M_TOK 1024
#define DMODEL 512
#define NHEAD 8
#define DHEAD 64

typedef __attribute__((ext_vector_type(8))) short short8;
typedef __attribute__((ext_vector_type(4))) float f32x4;
typedef __attribute__((ext_vector_type(4))) float float4v;

static __device__ __forceinline__ short f2bf(float f) {
    union { float f; unsigned u; } v; v.f = f;
    unsigned r = v.u + 0x7fffu + ((v.u >> 16) & 1u);
    return (short)(r >> 16);
}

#define GLOAD_LDS16(g, l) __builtin_amdgcn_global_load_lds( \
    (const __attribute__((address_space(1))) void*)(g), \
    (__attribute__((address_space(3))) void*)(l), 16, 0, 0)

// ---------------------------------------------------------------------------
// Pack: fp32 -> bf16. Weights stored TRANSPOSED B^T[n][k].
// ---------------------------------------------------------------------------
__global__ void pack_kernel(const float* __restrict__ xv, const float* __restrict__ xt,
                            const float* __restrict__ wq, const float* __restrict__ wk,
                            const float* __restrict__ wv, const float* __restrict__ wo,
                            short* __restrict__ xvb, short* __restrict__ xtb,
                            short* __restrict__ wqb, short* __restrict__ wkb,
                            short* __restrict__ wvb, short* __restrict__ wob) {
    int idx = blockIdx.x * 256 + threadIdx.x;
    int stride = gridDim.x * 256;
    const int CXV = N_TOK * DMODEL / 8;
    const int CXT = M_TOK * DMODEL / 8;
    const int NW  = DMODEL * DMODEL;
    for (int c = idx; c < CXV; c += stride) {
        float4v f0 = *(const float4v*)&xv[c * 8];
        float4v f1 = *(const float4v*)&xv[c * 8 + 4];
        short8 o;
        #pragma unroll
        for (int j = 0; j < 4; j++) { o[j] = f2bf(f0[j]); o[j + 4] = f2bf(f1[j]); }
        *(short8*)&xvb[c * 8] = o;
    }
    for (int c = idx; c < CXT; c += stride) {
        float4v f0 = *(const float4v*)&xt[c * 8];
        float4v f1 = *(const float4v*)&xt[c * 8 + 4];
        short8 o;
        #pragma unroll
        for (int j = 0; j < 4; j++) { o[j] = f2bf(f0[j]); o[j + 4] = f2bf(f1[j]); }
        *(short8*)&xtb[c * 8] = o;
    }
    for (int i = idx; i < NW; i += stride) {
        int n = i >> 9;
        int k = i & 511;
        int h = n >> 6, e = n & 63;
        int src = h * (DMODEL * DHEAD) + k * DHEAD + e;
        wqb[i] = f2bf(wq[src]);
        wkb[i] = f2bf(wk[src]);
        wvb[i] = f2bf(wv[src]);
        wob[i] = f2bf(wo[k * DMODEL + n]);
    }
}

// ---------------------------------------------------------------------------
// GEMM body: 64x64 tile, BK=64, double-buffered global_load_lds(16B), XOR
// granule swizzle on the GLOBAL source (linear LDS dest) and the same XOR on
// ds_read. 4 waves, wave (wr,wc) owns a 32x32 quadrant. 32 KB LDS ->
// 2-3 blocks/CU co-resident (the r6 regression was 1 block/CU).
// A: [Mrows][512] row-major. BT: [64 cols][512] row-major (pre-transposed).
// ---------------------------------------------------------------------------
template<typename EPI>
static __device__ __forceinline__ void gemm_body(const short* __restrict__ A,
                                                 const short* __restrict__ BT,
                                                 int m0, int n0, EPI epi) {
    __shared__ __align__(16) short As[2][64][64];   // 16 KB
    __shared__ __align__(16) short Bs[2][64][64];   // 16 KB
    int t = threadIdx.x;
    int lane = t & 63, w = t >> 6;
    int wr = w >> 1, wc = w & 1;
    int l15 = lane & 15, g = lane >> 4;
    int srow = lane >> 3;                 // 0..7
    int sgran = (lane & 7) ^ (srow & 7);  // swizzled source granule (involution)
    int sx = l15 & 7;

    const short* gA = A + (size_t)(m0 + w * 16 + srow) * DMODEL + sgran * 8;
    const short* gB = BT + (size_t)(n0 + w * 16 + srow) * DMODEL + sgran * 8;

    f32x4 acc[2][2] = {};

    // prologue: stage K-step 0 into buf 0 (per wave: rows w*16..w*16+15)
    GLOAD_LDS16(gA,                        &As[0][w * 16][0]);
    GLOAD_LDS16(gA + (size_t)8 * DMODEL,   &As[0][w * 16 + 8][0]);
    GLOAD_LDS16(gB,                        &Bs[0][w * 16][0]);
    GLOAD_LDS16(gB + (size_t)8 * DMODEL,   &Bs[0][w * 16 + 8][0]);
    __syncthreads();

    int buf = 0;
    #pragma unroll
    for (int step = 0; step < DMODEL / 64; ++step) {
        if (step < DMODEL / 64 - 1) {
            int kk = (step + 1) * 64;
            GLOAD_LDS16(gA + kk,                      &As[buf ^ 1][w * 16][0]);
            GLOAD_LDS16(gA + (size_t)8 * DMODEL + kk, &As[buf ^ 1][w * 16 + 8][0]);
            GLOAD_LDS16(gB + kk,                      &Bs[buf ^ 1][w * 16][0]);
            GLOAD_LDS16(gB + (size_t)8 * DMODEL + kk, &Bs[buf ^ 1][w * 16 + 8][0]);
        }
        #pragma unroll
        for (int ks = 0; ks < 2; ks++) {
            short8 a[2], b[2];
            #pragma unroll
            for (int fr = 0; fr < 2; fr++)
                a[fr] = *(short8*)&As[buf][wr * 32 + fr * 16 + l15][((ks * 4 + g) ^ sx) * 8];
            #pragma unroll
            for (int fc = 0; fc < 2; fc++)
                b[fc] = *(short8*)&Bs[buf][wc * 32 + fc * 16 + l15][((ks * 4 + g) ^ sx) * 8];
            #pragma unroll
            for (int fr = 0; fr < 2; fr++)
                #pragma unroll
                for (int fc = 0; fc < 2; fc++)
                    acc[fr][fc] = __builtin_amdgcn_mfma_f32_16x16x32_bf16(a[fr], b[fc], acc[fr][fc], 0, 0, 0);
        }
        __syncthreads();
        buf ^= 1;
    }

    #pragma unroll
    for (int fr = 0; fr < 2; fr++)
        #pragma unroll
        for (int fc = 0; fc < 2; fc++)
            #pragma unroll
            for (int r = 0; r < 4; r++) {
                int row = m0 + wr * 32 + fr * 16 + g * 4 + r;
                int col = n0 + wc * 32 + fc * 16 + l15;
                epi(row, col, acc[fr][fc][r]);
            }
}

// ---------------------------------------------------------------------------
// Q, K, V projections in ONE launch. flat grid 768 blocks:
//   bx<512: Q;  bx<640: K;  else: V (transposed out V^T[d][1024])
// ---------------------------------------------------------------------------
__global__ __launch_bounds__(256) void gemmQKV(const short* __restrict__ xvb,
                                               const short* __restrict__ xtb,
                                               const short* __restrict__ wqb,
                                               const short* __restrict__ wkb,
                                               const short* __restrict__ wvb,
                                               short* __restrict__ qb,
                                               short* __restrict__ kbm,
                                               short* __restrict__ vbt) {
    int bx = blockIdx.x;
    if (bx < 512) {
        short* C = qb;
        gemm_body(xvb, wqb, (bx >> 3) * 64, (bx & 7) * 64,
                  [&](int row, int col, float v) { C[(size_t)row * DMODEL + col] = f2bf(v); });
    } else if (bx < 640) {
        int b = bx - 512;
        short* C = kbm;
        gemm_body(xtb, wkb, (b >> 3) * 64, (b & 7) * 64,
                  [&](int row, int col, float v) { C[(size_t)row * DMODEL + col] = f2bf(v); });
    } else {
        int b = bx - 640;
        short* C = vbt;
        gemm_body(xtb, wvb, (b >> 3) * 64, (b & 7) * 64,
                  [&](int row, int col, float v) { C[(size_t)col * M_TOK + row] = f2bf(v); });
    }
}

// ---------------------------------------------------------------------------
// Final GEMM: out = Y * Wout(^T stored) + PE, fp32 out. 64x64 tile, 512 blk.
// ---------------------------------------------------------------------------
__global__ __launch_bounds__(256) void gemmOut(const short* __restrict__ A,
                                               const short* __restrict__ BT,
                                               float* __restrict__ Cout) {
    __shared__ float ifreq[256];
    ifreq[threadIdx.x] = expf(-(float)threadIdx.x * (9.210340371976184f / 512.0f));
    __syncthreads();
    int bx = blockIdx.x;
    gemm_body(A, BT, (bx >> 3) * 64, (bx & 7) * 64,
              [&](int row, int col, float v) {
                  float x = (float)row * ifreq[col >> 1];
                  float pe = (col & 1) ? cosf(x) : sinf(x);
                  Cout[(size_t)row * DMODEL + col] = v + pe;
              });
}

// ---------------------------------------------------------------------------
// Attention v5 (unchanged from round 5): LDS-staged, double-buffered,
// XOR-swizzled, block = 64 q x 1 head, no cross-wave merge.
// ---------------------------------------------------------------------------
__global__ __launch_bounds__(256) void attn_kernel(const short* __restrict__ Qb,
                                                   const short* __restrict__ Kb,
                                                   const short* __restrict__ VbT,
                                                   short* __restrict__ Yb) {
    __shared__ __align__(16) short Ks[2][64][64];
    __shared__ __align__(16) short Vs[2][64][64];
    __shared__ __align__(16) short Ps[4][16][72];

    int bid = blockIdx.x;
    int h = bid & 7;
    int qx = bid >> 3;
    int n0 = qx * 64;
    int t = threadIdx.x;
    int lane = t & 63, w = t >> 6;
    int l15 = lane & 15, g = lane >> 4;

    const short* Kh  = Kb + h * DHEAD;
    const short* VhT = VbT + (h * DHEAD) * M_TOK;

    int srow = (lane >> 3);
    int sgran = (lane & 7) ^ srow;
    const short* gK0 = Kh + (size_t)(w * 16 + srow) * DMODEL + sgran * 8;
    const short* gV0 = VhT + (size_t)(w * 16 + srow) * M_TOK + sgran * 8;

    const short* qrow = Qb + (size_t)(n0 + w * 16 + l15) * DMODEL + h * DHEAD;
    short8 qa0 = *(const short8*)(qrow + g * 8);
    short8 qa1 = *(const short8*)(qrow + 32 + g * 8);

    f32x4 acc[4] = {};
    f32x4 rsum = {};
    int sx = l15 & 7;

    {
        GLOAD_LDS16(gK0,                 &Ks[0][w * 16][0]);
        GLOAD_LDS16(gK0 + 8 * DMODEL,    &Ks[0][w * 16 + 8][0]);
        GLOAD_LDS16(gV0,                 &Vs[0][w * 16][0]);
        GLOAD_LDS16(gV0 + 8 * M_TOK,     &Vs[0][w * 16 + 8][0]);
    }
    __syncthreads();

    int buf = 0;
    for (int it = 0; it < 16; ++it) {
        if (it < 15) {
            int key0 = (it + 1) * 64;
            GLOAD_LDS16(gK0 + (size_t)key0 * DMODEL,             &Ks[buf ^ 1][w * 16][0]);
            GLOAD_LDS16(gK0 + (size_t)(key0 + 8) * DMODEL,       &Ks[buf ^ 1][w * 16 + 8][0]);
            GLOAD_LDS16(gV0 + key0,                              &Vs[buf ^ 1][w * 16][0]);
            GLOAD_LDS16(gV0 + key0 + 8 * M_TOK,                  &Vs[buf ^ 1][w * 16 + 8][0]);
        }
        #pragma unroll
        for (int kt = 0; kt < 4; kt++) {
            short8 kf0 = *(short8*)&Ks[buf][kt * 16 + l15][((g) ^ sx) * 8];
            short8 kf1 = *(short8*)&Ks[buf][kt * 16 + l15][((4 + g) ^ sx) * 8];
            f32x4 e = {};
            e = __builtin_amdgcn_mfma_f32_16x16x32_bf16(qa0, kf0, e, 0, 0, 0);
            e = __builtin_amdgcn_mfma_f32_16x16x32_bf16(qa1, kf1, e, 0, 0, 0);
            #pragma unroll
            for (int r = 0; r < 4; r++) {
                float p = exp2f(e[r] * 1.44269504f);
                rsum[r] += p;
                Ps[w][g * 4 + r][kt * 16 + l15] = f2bf(p);
            }
        }
        #pragma unroll
        for (int kb2 = 0; kb2 < 2; kb2++) {
            short8 pa = *(short8*)&Ps[w][l15][kb2 * 32 + g * 8];
            #pragma unroll
            for (int nt = 0; nt < 4; nt++) {
                short8 vf = *(short8*)&Vs[buf][nt * 16 + l15][((kb2 * 4 + g) ^ sx) * 8];
                acc[nt] = __builtin_amdgcn_mfma_f32_16x16x32_bf16(pa, vf, acc[nt], 0, 0, 0);
            }
        }
        __syncthreads();
        buf ^= 1;
    }

    #pragma unroll
    for (int r = 0; r < 4; r++) {
        float s = rsum[r];
        s += __shfl_xor(s, 1);
        s += __shfl_xor(s, 2);
        s += __shfl_xor(s, 4);
        s += __shfl_xor(s, 8);
        rsum[r] = s;
    }

    #pragma unroll
    for (int nt = 0; nt < 4; nt++)
        #pragma unroll
        for (int r = 0; r < 4; r++) {
            float y = acc[nt][r] / rsum[r];
            Yb[(size_t)(n0 + w * 16 + g * 4 + r) * DMODEL + h * DHEAD + nt * 16 + l15] = f2bf(y);
        }
}

// ---------------------------------------------------------------------------
extern "C" void kernel_launch(void* const* d_in, const int* in_sizes, int n_in,
                              void* d_out, int out_size, void* d_ws, size_t ws_size,
                              hipStream_t stream) {
    const float* xv = (const float*)d_in[0];
    const float* xt = (const float*)d_in[1];
    const float* wq = (const float*)d_in[2];
    const float* wk = (const float*)d_in[3];
    const float* wv = (const float*)d_in[4];
    const float* wo = (const float*)d_in[5];

    short* xvb = (short*)d_ws;              // 4096*512
    short* xtb = xvb + N_TOK * DMODEL;      // 1024*512
    short* wqb = xtb + M_TOK * DMODEL;      // 512*512 (B^T)
    short* wkb = wqb + DMODEL * DMODEL;
    short* wvb = wkb + DMODEL * DMODEL;
    short* wob = wvb + DMODEL * DMODEL;
    short* qb  = wob + DMODEL * DMODEL;     // 4096*512
    short* kbm = qb  + N_TOK * DMODEL;      // 1024*512
    short* vbt = kbm + M_TOK * DMODEL;      // 512*1024 (V^T)
    short* yb  = vbt + M_TOK * DMODEL;      // 4096*512

    pack_kernel<<<1024, 256, 0, stream>>>(xv, xt, wq, wk, wv, wo,
                                          xvb, xtb, wqb, wkb, wvb, wob);
    gemmQKV<<<768, 256, 0, stream>>>(xvb, xtb, wqb, wkb, wvb, qb, kbm, vbt);
    attn_kernel<<<512, 256, 0, stream>>>(qb, kbm, vbt, yb);
    gemmOut<<<512, 256, 0, stream>>>(yb, wob, (float*)d_out);
}

// Round 8
// 62.652 us; speedup vs baseline: 1.1708x; 1.1708x over previous
//
#include <hip/hip_runtime.h>
#include <hip/hip_bf16.h>
#include <math.h>

#define N_TOK 4096
#define M_TOK 1024
#define DMODEL 512
#define NHEAD 8
#define DHEAD 64

typedef __attribute__((ext_vector_type(8))) short short8;
typedef __attribute__((ext_vector_type(4))) float f32x4;
typedef __attribute__((ext_vector_type(4))) float float4v;
typedef __attribute__((ext_vector_type(2))) float float2v;

static __device__ __forceinline__ short f2bf(float f) {
    union { float f; unsigned u; } v; v.f = f;
    unsigned r = v.u + 0x7fffu + ((v.u >> 16) & 1u);
    return (short)(r >> 16);
}

#define GLOAD_LDS16(g, l) __builtin_amdgcn_global_load_lds( \
    (const __attribute__((address_space(1))) void*)(g), \
    (__attribute__((address_space(3))) void*)(l), 16, 0, 0)

// ---------------------------------------------------------------------------
// Pack: fp32 -> bf16 (weights TRANSPOSED B^T[n][k]) + PE table (f32).
// ---------------------------------------------------------------------------
__global__ void pack_kernel(const float* __restrict__ xv, const float* __restrict__ xt,
                            const float* __restrict__ wq, const float* __restrict__ wk,
                            const float* __restrict__ wv, const float* __restrict__ wo,
                            short* __restrict__ xvb, short* __restrict__ xtb,
                            short* __restrict__ wqb, short* __restrict__ wkb,
                            short* __restrict__ wvb, short* __restrict__ wob,
                            float* __restrict__ pe) {
    int idx = blockIdx.x * 256 + threadIdx.x;
    int stride = gridDim.x * 256;
    const int CXV = N_TOK * DMODEL / 8;
    const int CXT = M_TOK * DMODEL / 8;
    const int NW  = DMODEL * DMODEL;
    const int NPE = N_TOK * (DMODEL / 2);
    for (int c = idx; c < CXV; c += stride) {
        float4v f0 = *(const float4v*)&xv[c * 8];
        float4v f1 = *(const float4v*)&xv[c * 8 + 4];
        short8 o;
        #pragma unroll
        for (int j = 0; j < 4; j++) { o[j] = f2bf(f0[j]); o[j + 4] = f2bf(f1[j]); }
        *(short8*)&xvb[c * 8] = o;
    }
    for (int c = idx; c < CXT; c += stride) {
        float4v f0 = *(const float4v*)&xt[c * 8];
        float4v f1 = *(const float4v*)&xt[c * 8 + 4];
        short8 o;
        #pragma unroll
        for (int j = 0; j < 4; j++) { o[j] = f2bf(f0[j]); o[j + 4] = f2bf(f1[j]); }
        *(short8*)&xtb[c * 8] = o;
    }
    for (int i = idx; i < NW; i += stride) {
        int n = i >> 9;
        int k = i & 511;
        int h = n >> 6, e = n & 63;
        int src = h * (DMODEL * DHEAD) + k * DHEAD + e;
        wqb[i] = f2bf(wq[src]);
        wkb[i] = f2bf(wk[src]);
        wvb[i] = f2bf(wv[src]);
        wob[i] = f2bf(wo[k * DMODEL + n]);
    }
    // PE table: pe[row][2i]=sin(row/freq_i), pe[row][2i+1]=cos(row/freq_i)
    for (int i = idx; i < NPE; i += stride) {
        int row = i >> 8;
        int p = i & 255;
        float fr = __expf(-(float)p * (9.210340371976184f / 512.0f));
        float x = (float)row * fr;
        float s, c;
        __sincosf(x, &s, &c);
        float2v sc; sc[0] = s; sc[1] = c;
        *(float2v*)&pe[(size_t)row * DMODEL + p * 2] = sc;
    }
}

// ---------------------------------------------------------------------------
// GEMM body (r5-proven structure): 64x64 tile, BK=64, padded LDS, vector
// reg-staging with explicit async-split (stage -> barrier -> issue next
// loads -> MFMA -> barrier). 4 waves, wave (wr,wc) owns a 32x32 quadrant.
// A: [Mrows][512] row-major. BT: [64 cols][512] row-major (pre-transposed).
// ---------------------------------------------------------------------------
template<typename EPI>
static __device__ __forceinline__ void gemm_body(const short* __restrict__ A,
                                                 const short* __restrict__ BT,
                                                 int m0, int n0, EPI epi) {
    __shared__ __align__(16) short As[64][72];
    __shared__ __align__(16) short Bs[64][72];
    int t = threadIdx.x;
    int lane = t & 63, w = t >> 6;
    int wr = w >> 1, wc = w & 1;
    int l15 = lane & 15, g = lane >> 4;

    int row = t >> 2, c0 = (t & 3) * 16;
    const short* gA = A + (size_t)(m0 + row) * DMODEL + c0;
    const short* gB = BT + (size_t)(n0 + row) * DMODEL + c0;

    short8 ra0 = *(const short8*)gA;
    short8 ra1 = *(const short8*)(gA + 8);
    short8 rb0 = *(const short8*)gB;
    short8 rb1 = *(const short8*)(gB + 8);

    f32x4 acc[2][2] = {};
    #pragma unroll
    for (int step = 0; step < DMODEL / 64; ++step) {
        *(short8*)&As[row][c0]     = ra0;
        *(short8*)&As[row][c0 + 8] = ra1;
        *(short8*)&Bs[row][c0]     = rb0;
        *(short8*)&Bs[row][c0 + 8] = rb1;
        __syncthreads();
        if (step < DMODEL / 64 - 1) {           // issue next-step loads early
            gA += 64; gB += 64;
            ra0 = *(const short8*)gA;
            ra1 = *(const short8*)(gA + 8);
            rb0 = *(const short8*)gB;
            rb1 = *(const short8*)(gB + 8);
        }
        #pragma unroll
        for (int ks = 0; ks < 2; ks++) {
            short8 a[2], b[2];
            #pragma unroll
            for (int fr = 0; fr < 2; fr++) a[fr] = *(short8*)&As[wr * 32 + fr * 16 + l15][ks * 32 + g * 8];
            #pragma unroll
            for (int fc = 0; fc < 2; fc++) b[fc] = *(short8*)&Bs[wc * 32 + fc * 16 + l15][ks * 32 + g * 8];
            #pragma unroll
            for (int fr = 0; fr < 2; fr++)
                #pragma unroll
                for (int fc = 0; fc < 2; fc++)
                    acc[fr][fc] = __builtin_amdgcn_mfma_f32_16x16x32_bf16(a[fr], b[fc], acc[fr][fc], 0, 0, 0);
        }
        __syncthreads();
    }
    #pragma unroll
    for (int fr = 0; fr < 2; fr++)
        #pragma unroll
        for (int fc = 0; fc < 2; fc++)
            #pragma unroll
            for (int r = 0; r < 4; r++) {
                int orow = m0 + wr * 32 + fr * 16 + g * 4 + r;
                int ocol = n0 + wc * 32 + fc * 16 + l15;
                epi(orow, ocol, acc[fr][fc][r]);
            }
}

// ---------------------------------------------------------------------------
// Q, K, V projections in ONE launch. grid (96, 8):
//   bx<64: Q;  bx<80: K;  else: V (transposed out V^T[d][1024])
// ---------------------------------------------------------------------------
__global__ __launch_bounds__(256) void gemmQKV(const short* __restrict__ xvb,
                                               const short* __restrict__ xtb,
                                               const short* __restrict__ wqb,
                                               const short* __restrict__ wkb,
                                               const short* __restrict__ wvb,
                                               short* __restrict__ qb,
                                               short* __restrict__ kbm,
                                               short* __restrict__ vbt) {
    int bx = blockIdx.x;
    int n0 = blockIdx.y * 64;
    if (bx < 64) {
        short* C = qb;
        gemm_body(xvb, wqb, bx * 64, n0,
                  [&](int row, int col, float v) { C[(size_t)row * DMODEL + col] = f2bf(v); });
    } else if (bx < 80) {
        short* C = kbm;
        gemm_body(xtb, wkb, (bx - 64) * 64, n0,
                  [&](int row, int col, float v) { C[(size_t)row * DMODEL + col] = f2bf(v); });
    } else {
        short* C = vbt;
        gemm_body(xtb, wvb, (bx - 80) * 64, n0,
                  [&](int row, int col, float v) { C[(size_t)col * M_TOK + row] = f2bf(v); });
    }
}

// ---------------------------------------------------------------------------
// Final GEMM: out = Y * Wout(^T stored) + PE(table), fp32 out. 64x64 tile.
// ---------------------------------------------------------------------------
__global__ __launch_bounds__(256) void gemmOut(const short* __restrict__ A,
                                               const short* __restrict__ BT,
                                               const float* __restrict__ pe,
                                               float* __restrict__ Cout) {
    gemm_body(A, BT, blockIdx.x * 64, blockIdx.y * 64,
              [&](int row, int col, float v) {
                  size_t o = (size_t)row * DMODEL + col;
                  Cout[o] = v + pe[o];
              });
}

// ---------------------------------------------------------------------------
// Attention v5 (unchanged): LDS-staged, double-buffered, XOR-swizzled,
// block = 64 q x 1 head, no cross-wave merge.
// ---------------------------------------------------------------------------
__global__ __launch_bounds__(256) void attn_kernel(const short* __restrict__ Qb,
                                                   const short* __restrict__ Kb,
                                                   const short* __restrict__ VbT,
                                                   short* __restrict__ Yb) {
    __shared__ __align__(16) short Ks[2][64][64];
    __shared__ __align__(16) short Vs[2][64][64];
    __shared__ __align__(16) short Ps[4][16][72];

    int bid = blockIdx.x;
    int h = bid & 7;
    int qx = bid >> 3;
    int n0 = qx * 64;
    int t = threadIdx.x;
    int lane = t & 63, w = t >> 6;
    int l15 = lane & 15, g = lane >> 4;

    const short* Kh  = Kb + h * DHEAD;
    const short* VhT = VbT + (h * DHEAD) * M_TOK;

    int srow = (lane >> 3);
    int sgran = (lane & 7) ^ srow;
    const short* gK0 = Kh + (size_t)(w * 16 + srow) * DMODEL + sgran * 8;
    const short* gV0 = VhT + (size_t)(w * 16 + srow) * M_TOK + sgran * 8;

    const short* qrow = Qb + (size_t)(n0 + w * 16 + l15) * DMODEL + h * DHEAD;
    short8 qa0 = *(const short8*)(qrow + g * 8);
    short8 qa1 = *(const short8*)(qrow + 32 + g * 8);

    f32x4 acc[4] = {};
    f32x4 rsum = {};
    int sx = l15 & 7;

    {
        GLOAD_LDS16(gK0,                 &Ks[0][w * 16][0]);
        GLOAD_LDS16(gK0 + 8 * DMODEL,    &Ks[0][w * 16 + 8][0]);
        GLOAD_LDS16(gV0,                 &Vs[0][w * 16][0]);
        GLOAD_LDS16(gV0 + 8 * M_TOK,     &Vs[0][w * 16 + 8][0]);
    }
    __syncthreads();

    int buf = 0;
    for (int it = 0; it < 16; ++it) {
        if (it < 15) {
            int key0 = (it + 1) * 64;
            GLOAD_LDS16(gK0 + (size_t)key0 * DMODEL,             &Ks[buf ^ 1][w * 16][0]);
            GLOAD_LDS16(gK0 + (size_t)(key0 + 8) * DMODEL,       &Ks[buf ^ 1][w * 16 + 8][0]);
            GLOAD_LDS16(gV0 + key0,                              &Vs[buf ^ 1][w * 16][0]);
            GLOAD_LDS16(gV0 + key0 + 8 * M_TOK,                  &Vs[buf ^ 1][w * 16 + 8][0]);
        }
        #pragma unroll
        for (int kt = 0; kt < 4; kt++) {
            short8 kf0 = *(short8*)&Ks[buf][kt * 16 + l15][((g) ^ sx) * 8];
            short8 kf1 = *(short8*)&Ks[buf][kt * 16 + l15][((4 + g) ^ sx) * 8];
            f32x4 e = {};
            e = __builtin_amdgcn_mfma_f32_16x16x32_bf16(qa0, kf0, e, 0, 0, 0);
            e = __builtin_amdgcn_mfma_f32_16x16x32_bf16(qa1, kf1, e, 0, 0, 0);
            #pragma unroll
            for (int r = 0; r < 4; r++) {
                float p = exp2f(e[r] * 1.44269504f);
                rsum[r] += p;
                Ps[w][g * 4 + r][kt * 16 + l15] = f2bf(p);
            }
        }
        #pragma unroll
        for (int kb2 = 0; kb2 < 2; kb2++) {
            short8 pa = *(short8*)&Ps[w][l15][kb2 * 32 + g * 8];
            #pragma unroll
            for (int nt = 0; nt < 4; nt++) {
                short8 vf = *(short8*)&Vs[buf][nt * 16 + l15][((kb2 * 4 + g) ^ sx) * 8];
                acc[nt] = __builtin_amdgcn_mfma_f32_16x16x32_bf16(pa, vf, acc[nt], 0, 0, 0);
            }
        }
        __syncthreads();
        buf ^= 1;
    }

    #pragma unroll
    for (int r = 0; r < 4; r++) {
        float s = rsum[r];
        s += __shfl_xor(s, 1);
        s += __shfl_xor(s, 2);
        s += __shfl_xor(s, 4);
        s += __shfl_xor(s, 8);
        rsum[r] = s;
    }

    #pragma unroll
    for (int nt = 0; nt < 4; nt++)
        #pragma unroll
        for (int r = 0; r < 4; r++) {
            float y = acc[nt][r] / rsum[r];
            Yb[(size_t)(n0 + w * 16 + g * 4 + r) * DMODEL + h * DHEAD + nt * 16 + l15] = f2bf(y);
        }
}

// ---------------------------------------------------------------------------
extern "C" void kernel_launch(void* const* d_in, const int* in_sizes, int n_in,
                              void* d_out, int out_size, void* d_ws, size_t ws_size,
                              hipStream_t stream) {
    const float* xv = (const float*)d_in[0];
    const float* xt = (const float*)d_in[1];
    const float* wq = (const float*)d_in[2];
    const float* wk = (const float*)d_in[3];
    const float* wv = (const float*)d_in[4];
    const float* wo = (const float*)d_in[5];

    short* xvb = (short*)d_ws;              // 4096*512
    short* xtb = xvb + N_TOK * DMODEL;      // 1024*512
    short* wqb = xtb + M_TOK * DMODEL;      // 512*512 (B^T)
    short* wkb = wqb + DMODEL * DMODEL;
    short* wvb = wkb + DMODEL * DMODEL;
    short* wob = wvb + DMODEL * DMODEL;
    short* qb  = wob + DMODEL * DMODEL;     // 4096*512
    short* kbm = qb  + N_TOK * DMODEL;      // 1024*512
    short* vbt = kbm + M_TOK * DMODEL;      // 512*1024 (V^T)
    short* yb  = vbt + M_TOK * DMODEL;      // 4096*512
    float* pe  = (float*)(yb + N_TOK * DMODEL);  // 4096*512 f32 (16B-aligned)

    pack_kernel<<<1024, 256, 0, stream>>>(xv, xt, wq, wk, wv, wo,
                                          xvb, xtb, wqb, wkb, wvb, wob, pe);
    gemmQKV<<<dim3(96, 8), 256, 0, stream>>>(xvb, xtb, wqb, wkb, wvb, qb, kbm, vbt);
    attn_kernel<<<512, 256, 0, stream>>>(qb, kbm, vbt, yb);
    gemmOut<<<dim3(64, 8), 256, 0, stream>>>(yb, wob, pe, (float*)d_out);
}